// Round 1
// baseline (577.416 us; speedup 1.0000x reference)
//
#include <hip/hip_runtime.h>
#include <hip/hip_bf16.h>

// ---------------- types ----------------
typedef __attribute__((ext_vector_type(8))) __bf16 bf16x8;
typedef __attribute__((ext_vector_type(4))) float  f32x4;

#define H_DIM 1152

// ---------------- kernel 1: smooth-scale + per-token prescale + NVFP4 fake quant -> bf16 ----------------
// one block (128 threads) per token
__global__ __launch_bounds__(128) void quant_kernel(
    const float* __restrict__ x, const float* __restrict__ smooth,
    unsigned short* __restrict__ xq)
{
    __shared__ float xs[H_DIM];
    __shared__ float wmax_s[2];
    const int t = blockIdx.x;
    const int tid = threadIdx.x;
    const float* xrow = x + (size_t)t * H_DIM;

    // phase A: x_s = x * smooth, stage in LDS, partial max
    float m = 0.f;
    for (int i = tid; i < H_DIM; i += 128) {
        float v = xrow[i] * smooth[i];
        xs[i] = v;
        m = fmaxf(m, fabsf(v));
    }
    // wave butterfly max
    for (int off = 32; off > 0; off >>= 1)
        m = fmaxf(m, __shfl_xor(m, off, 64));
    if ((tid & 63) == 0) wmax_s[tid >> 6] = m;
    __syncthreads();

    const float token_max = fmaxf(fmaxf(wmax_s[0], wmax_s[1]), 1e-12f);
    const float pre_scale = token_max / 6.0f;

    // phase B: 72 blocks of 16; thread tid handles block tid
    if (tid < H_DIM / 16) {
        const int base = tid * 16;
        float vals[16];
        float amax = 0.f;
        for (int j = 0; j < 16; ++j) {
            float v = xs[base + j] / pre_scale;   // exact replication of reference op order
            vals[j] = v;
            amax = fmaxf(amax, fabsf(v));
        }
        amax = fmaxf(amax, 1e-12f);
        const float scale = amax / 6.0f;
        alignas(16) __hip_bfloat16 outv[16];
        for (int j = 0; j < 16; ++j) {
            float av = fabsf(vals[j]);
            float xn = av / scale;
            // nearest NVFP4 level, ties to lower (== fp32 argmin: Sterbenz-exact comparisons)
            float lvl = xn <= 0.25f ? 0.0f
                      : xn <= 0.75f ? 0.5f
                      : xn <= 1.25f ? 1.0f
                      : xn <= 1.75f ? 1.5f
                      : xn <= 2.5f  ? 2.0f
                      : xn <= 3.5f  ? 3.0f
                      : xn <= 5.0f  ? 4.0f : 6.0f;
            float q = copysignf(lvl * scale, vals[j]) * pre_scale;
            outv[j] = __float2bfloat16(q);
        }
        uint4* dst = (uint4*)(xq + (size_t)t * H_DIM + base);
        dst[0] = *(const uint4*)&outv[0];
        dst[1] = *(const uint4*)&outv[8];
    }
}

// ---------------- kernel 2: w fp32 -> bf16 ----------------
__global__ __launch_bounds__(256) void wconv_kernel(
    const float* __restrict__ w, unsigned short* __restrict__ wq, int n)
{
    int i = (blockIdx.x * 256 + threadIdx.x) * 4;
    if (i < n) {
        float4 v = *(const float4*)(w + i);
        alignas(8) __hip_bfloat16 o[4];
        o[0] = __float2bfloat16(v.x);
        o[1] = __float2bfloat16(v.y);
        o[2] = __float2bfloat16(v.z);
        o[3] = __float2bfloat16(v.w);
        *(uint2*)(wq + i) = *(const uint2*)o;
    }
}

// ---------------- async global->LDS 16B helper ----------------
__device__ __forceinline__ void async_copy16(const void* gptr, void* lptr)
{
    __builtin_amdgcn_global_load_lds(
        (const __attribute__((address_space(1))) unsigned int*)gptr,
        (__attribute__((address_space(3))) unsigned int*)lptr,
        16, 0, 0);
}

// ---------------- kernel 3: bf16 GEMM, C[t,o] = sum_k A[t,k]*B[o,k] + bias[o] ----------------
// 128x128 tile, BK=32, 256 threads (4 waves, each 64x64 = 4x4 frags of 16x16x32)
__global__ __launch_bounds__(256) void gemm_bt_kernel(
    const unsigned short* __restrict__ A,  // [M,K] bf16 bits
    const unsigned short* __restrict__ B,  // [N,K] bf16 bits
    const float* __restrict__ bias,        // [N]
    float* __restrict__ C,                 // [M,N]
    int M, int N, int K)
{
    __shared__ unsigned short sA[128 * 32];
    __shared__ unsigned short sB[128 * 32];

    const int tid  = threadIdx.x;
    const int wave = tid >> 6;
    const int lane = tid & 63;
    const int m0 = blockIdx.y * 128;
    const int n0 = blockIdx.x * 128;
    const int wave_m = (wave & 1) * 64;
    const int wave_n = (wave >> 1) * 64;
    const int lane16 = lane & 15;
    const int quad   = lane >> 4;

    // staging lane geometry: 16 rows x 32 cols per instruction (64 lanes x 8 bf16)
    const int rowA = lane >> 2;        // 0..15
    const int colA = (lane & 3) * 8;   // 0,8,16,24

    f32x4 acc[4][4] = {};

    for (int k0 = 0; k0 < K; k0 += 32) {
        __syncthreads();   // previous compute done before overwrite
        #pragma unroll
        for (int s = 0; s < 2; ++s) {
            const int R = wave * 32 + s * 16;                 // wave-uniform
            async_copy16(A + (size_t)(m0 + R + rowA) * K + k0 + colA, sA + R * 32);
            async_copy16(B + (size_t)(n0 + R + rowA) * K + k0 + colA, sB + R * 32);
        }
        __syncthreads();   // drains vmcnt, staged tile visible

        bf16x8 a[4], b[4];
        #pragma unroll
        for (int i = 0; i < 4; ++i)
            a[i] = *(const bf16x8*)(sA + (wave_m + i * 16 + lane16) * 32 + quad * 8);
        #pragma unroll
        for (int j = 0; j < 4; ++j)
            b[j] = *(const bf16x8*)(sB + (wave_n + j * 16 + lane16) * 32 + quad * 8);
        #pragma unroll
        for (int i = 0; i < 4; ++i)
            #pragma unroll
            for (int j = 0; j < 4; ++j)
                acc[i][j] = __builtin_amdgcn_mfma_f32_16x16x32_bf16(a[i], b[j], acc[i][j], 0, 0, 0);
    }

    // epilogue: C/D layout col=lane&15, row=quad*4+reg
    #pragma unroll
    for (int i = 0; i < 4; ++i) {
        const int m = m0 + wave_m + i * 16 + quad * 4;
        #pragma unroll
        for (int j = 0; j < 4; ++j) {
            const int n = n0 + wave_n + j * 16 + lane16;
            const float bv = bias[n];
            float* cp = C + (size_t)m * N + n;
            #pragma unroll
            for (int r = 0; r < 4; ++r)
                cp[(size_t)r * N] = acc[i][j][r] + bv;
        }
    }
}

// ---------------- launch ----------------
extern "C" void kernel_launch(void* const* d_in, const int* in_sizes, int n_in,
                              void* d_out, int out_size, void* d_ws, size_t ws_size,
                              hipStream_t stream)
{
    const float* x      = (const float*)d_in[0];
    const float* w      = (const float*)d_in[1];
    const float* smooth = (const float*)d_in[2];
    const float* bias   = (const float*)d_in[3];
    float* out = (float*)d_out;

    const int H = in_sizes[2];            // 1152
    const int T = in_sizes[0] / H;        // 16384
    const int O = in_sizes[3];            // 4608

    unsigned short* xq = (unsigned short*)d_ws;
    unsigned short* wq = (unsigned short*)((char*)d_ws + (size_t)T * H * sizeof(unsigned short));

    quant_kernel<<<T, 128, 0, stream>>>(x, smooth, xq);
    wconv_kernel<<<(O * H / 4 + 255) / 256, 256, 0, stream>>>(w, wq, O * H);

    dim3 grid(O / 128, T / 128);
    gemm_bt_kernel<<<grid, 256, 0, stream>>>(xq, wq, bias, out, T, O, H);
}

// Round 2
// 569.611 us; speedup vs baseline: 1.0137x; 1.0137x over previous
//
#include <hip/hip_runtime.h>
#include <hip/hip_bf16.h>

// ---------------- types ----------------
typedef __attribute__((ext_vector_type(8))) _Float16 f16x8;
typedef __attribute__((ext_vector_type(4))) float  f32x4;

#define H_DIM 1152
#define H_VEC (H_DIM / 4)   // 288 float4 per token

__device__ __forceinline__ float nvfp4_level(float xn) {
    // nearest NVFP4 level, ties to lower == fp32 argmin over |xn - level|
    return xn <= 0.25f ? 0.0f
         : xn <= 0.75f ? 0.5f
         : xn <= 1.25f ? 1.0f
         : xn <= 1.75f ? 1.5f
         : xn <= 2.5f  ? 2.0f
         : xn <= 3.5f  ? 3.0f
         : xn <= 5.0f  ? 4.0f : 6.0f;
}

// ---------------- kernel 1: smooth + prescale + NVFP4 fake quant -> fp16 ----------------
// one wave (64 lanes) per token, fully register-resident, no LDS, no barriers.
// lane l holds float4 indices {l, l+64, l+128, l+192} and (l&31)+256.
// a 16-elem NVFP4 block == float4s of 4 consecutive lanes at one index slot.
__global__ __launch_bounds__(64) void quant_kernel(
    const float4* __restrict__ x4, const float4* __restrict__ s4,
    _Float16* __restrict__ xq)
{
    const int t    = blockIdx.x;
    const int lane = threadIdx.x;
    const float4* xrow = x4 + (size_t)t * H_VEC;

    float4 v[5];
    int    fidx[5];
    float  m = 0.f;
    #pragma unroll
    for (int i = 0; i < 5; ++i) {
        const int f = (i < 4) ? (lane + 64 * i) : (256 + (lane & 31));
        fidx[i] = f;
        const float4 xx = xrow[f];
        const float4 ss = s4[f];
        float4 vv;
        vv.x = xx.x * ss.x; vv.y = xx.y * ss.y;
        vv.z = xx.z * ss.z; vv.w = xx.w * ss.w;
        v[i] = vv;
        m = fmaxf(m, fmaxf(fmaxf(fabsf(vv.x), fabsf(vv.y)),
                           fmaxf(fabsf(vv.z), fabsf(vv.w))));
    }
    // token max (upper lanes' tail slot duplicates lower lanes' -> max unchanged)
    #pragma unroll
    for (int off = 32; off; off >>= 1)
        m = fmaxf(m, __shfl_xor(m, off, 64));
    const float pre_scale = fmaxf(m, 1e-12f) / 6.0f;

    #pragma unroll
    for (int i = 0; i < 5; ++i) {
        float4 p;
        p.x = v[i].x / pre_scale;
        p.y = v[i].y / pre_scale;
        p.z = v[i].z / pre_scale;
        p.w = v[i].w / pre_scale;
        float g = fmaxf(fmaxf(fabsf(p.x), fabsf(p.y)),
                        fmaxf(fabsf(p.z), fabsf(p.w)));
        // 16-block amax over 4 consecutive lanes
        g = fmaxf(g, __shfl_xor(g, 1, 64));
        g = fmaxf(g, __shfl_xor(g, 2, 64));
        const float scale = fmaxf(g, 1e-12f) / 6.0f;

        alignas(8) _Float16 o[4];
        {
            float q;
            q = copysignf(nvfp4_level(fabsf(p.x) / scale) * scale, p.x) * pre_scale;
            o[0] = (_Float16)q;
            q = copysignf(nvfp4_level(fabsf(p.y) / scale) * scale, p.y) * pre_scale;
            o[1] = (_Float16)q;
            q = copysignf(nvfp4_level(fabsf(p.z) / scale) * scale, p.z) * pre_scale;
            o[2] = (_Float16)q;
            q = copysignf(nvfp4_level(fabsf(p.w) / scale) * scale, p.w) * pre_scale;
            o[3] = (_Float16)q;
        }
        if (i < 4 || lane < 32) {
            _Float16* dst = xq + (size_t)t * H_DIM + fidx[i] * 4;
            *(uint2*)dst = *(const uint2*)o;
        }
    }
}

// ---------------- kernel 2: w fp32 -> fp16 ----------------
__global__ __launch_bounds__(256) void wconv_kernel(
    const float* __restrict__ w, _Float16* __restrict__ wq, int n)
{
    int i = (blockIdx.x * 256 + threadIdx.x) * 4;
    if (i < n) {
        float4 v = *(const float4*)(w + i);
        alignas(8) _Float16 o[4];
        o[0] = (_Float16)v.x;
        o[1] = (_Float16)v.y;
        o[2] = (_Float16)v.z;
        o[3] = (_Float16)v.w;
        *(uint2*)(wq + i) = *(const uint2*)o;
    }
}

// ---------------- async global->LDS 16B helper ----------------
__device__ __forceinline__ void async_copy16(const void* gptr, void* lptr)
{
    __builtin_amdgcn_global_load_lds(
        (const __attribute__((address_space(1))) unsigned int*)gptr,
        (__attribute__((address_space(3))) unsigned int*)lptr,
        16, 0, 0);
}

// ---------------- kernel 3: fp16 GEMM, C[t,o] = sum_k A[t,k]*B[o,k] + bias[o] ----------------
// 128x128 tile, BK=32, 256 threads (4 waves, each 64x64 = 4x4 frags of 16x16x32)
__global__ __launch_bounds__(256) void gemm_bt_kernel(
    const _Float16* __restrict__ A,  // [M,K]
    const _Float16* __restrict__ B,  // [N,K]
    const float* __restrict__ bias,  // [N]
    float* __restrict__ C,           // [M,N]
    int M, int N, int K)
{
    __shared__ _Float16 sA[128 * 32];
    __shared__ _Float16 sB[128 * 32];

    const int tid  = threadIdx.x;
    const int wave = tid >> 6;
    const int lane = tid & 63;
    const int m0 = blockIdx.y * 128;
    const int n0 = blockIdx.x * 128;
    const int wave_m = (wave & 1) * 64;
    const int wave_n = (wave >> 1) * 64;
    const int lane16 = lane & 15;
    const int quad   = lane >> 4;

    // staging lane geometry: 16 rows x 32 cols per instruction (64 lanes x 8 fp16)
    const int rowA = lane >> 2;        // 0..15
    const int colA = (lane & 3) * 8;   // 0,8,16,24

    f32x4 acc[4][4] = {};

    for (int k0 = 0; k0 < K; k0 += 32) {
        __syncthreads();   // previous compute done before overwrite
        #pragma unroll
        for (int s = 0; s < 2; ++s) {
            const int R = wave * 32 + s * 16;                 // wave-uniform
            async_copy16(A + (size_t)(m0 + R + rowA) * K + k0 + colA, sA + R * 32);
            async_copy16(B + (size_t)(n0 + R + rowA) * K + k0 + colA, sB + R * 32);
        }
        __syncthreads();   // drains vmcnt, staged tile visible

        f16x8 a[4], b[4];
        #pragma unroll
        for (int i = 0; i < 4; ++i)
            a[i] = *(const f16x8*)(sA + (wave_m + i * 16 + lane16) * 32 + quad * 8);
        #pragma unroll
        for (int j = 0; j < 4; ++j)
            b[j] = *(const f16x8*)(sB + (wave_n + j * 16 + lane16) * 32 + quad * 8);
        #pragma unroll
        for (int i = 0; i < 4; ++i)
            #pragma unroll
            for (int j = 0; j < 4; ++j)
                acc[i][j] = __builtin_amdgcn_mfma_f32_16x16x32_f16(a[i], b[j], acc[i][j], 0, 0, 0);
    }

    // epilogue: C/D layout col=lane&15, row=quad*4+reg
    #pragma unroll
    for (int i = 0; i < 4; ++i) {
        const int m = m0 + wave_m + i * 16 + quad * 4;
        #pragma unroll
        for (int j = 0; j < 4; ++j) {
            const int n = n0 + wave_n + j * 16 + lane16;
            const float bv = bias[n];
            float* cp = C + (size_t)m * N + n;
            #pragma unroll
            for (int r = 0; r < 4; ++r)
                cp[(size_t)r * N] = acc[i][j][r] + bv;
        }
    }
}

// ---------------- launch ----------------
extern "C" void kernel_launch(void* const* d_in, const int* in_sizes, int n_in,
                              void* d_out, int out_size, void* d_ws, size_t ws_size,
                              hipStream_t stream)
{
    const float* x      = (const float*)d_in[0];
    const float* w      = (const float*)d_in[1];
    const float* smooth = (const float*)d_in[2];
    const float* bias   = (const float*)d_in[3];
    float* out = (float*)d_out;

    const int H = in_sizes[2];            // 1152
    const int T = in_sizes[0] / H;        // 16384
    const int O = in_sizes[3];            // 4608

    _Float16* xq = (_Float16*)d_ws;
    _Float16* wq = (_Float16*)((char*)d_ws + (size_t)T * H * sizeof(_Float16));

    quant_kernel<<<T, 64, 0, stream>>>((const float4*)x, (const float4*)smooth, xq);
    wconv_kernel<<<(O * H / 4 + 255) / 256, 256, 0, stream>>>(w, wq, O * H);

    dim3 grid(O / 128, T / 128);
    gemm_bt_kernel<<<grid, 256, 0, stream>>>(xq, wq, bias, out, T, O, H);
}